// Round 3
// baseline (272.714 us; speedup 1.0000x reference)
//
#include <hip/hip_runtime.h>
#include <hip/hip_bf16.h>

#define D 128
#define NPB 64
#define SCAN_T 256
#define SCAN_IT 8
#define SCAN_TILE (SCAN_T * SCAN_IT)   // 2048

typedef __attribute__((ext_vector_type(8))) short short8;   // 8 bf16 (4 VGPRs)
typedef __attribute__((ext_vector_type(4))) float f32x4;

static __device__ __forceinline__ unsigned short f32_to_bf16(float f) {
    unsigned int u = __float_as_uint(f);
    u = (u + 0x7FFFu + ((u >> 16) & 1u)) >> 16;   // RNE
    return (unsigned short)u;
}
static __device__ __forceinline__ float bf16lo(unsigned int r) {
    return __uint_as_float(r << 16);
}
static __device__ __forceinline__ float bf16hi(unsigned int r) {
    return __uint_as_float(r & 0xFFFF0000u);
}

// ---------------------------------------------------------------------------
// K0: convert w_embed rows into MFMA B-fragment layout (bf16), two sets:
//     set0 = rows 0..127 (src proj), set1 = rows 130..257 (dst proj).
//     frag (set,ks,nt,lane) holds B[k=ks*32+(lane>>4)*8+j][col=nt*16+(lane&15)]
// ---------------------------------------------------------------------------
__global__ void __launch_bounds__(256)
wconv_kernel(const float* __restrict__ w_embed, unsigned short* __restrict__ w_frag)
{
    int t = blockIdx.x * 256 + threadIdx.x;     // 4096 lane-frags total
    if (t >= 4096) return;
    int set  = t >> 11;
    int ks   = (t >> 9) & 3;
    int nt   = (t >> 6) & 7;
    int lane = t & 63;
    int wrow0 = set ? 130 : 0;
    int col   = nt * 16 + (lane & 15);
    int kbase = ks * 32 + (lane >> 4) * 8;
    unsigned short* dst = w_frag + (size_t)t * 8;
#pragma unroll
    for (int j = 0; j < 8; ++j)
        dst[j] = f32_to_bf16(w_embed[(size_t)(wrow0 + kbase + j) * D + col]);
}

// ---------------------------------------------------------------------------
// K1: MFMA node projection.  proj[n] = bf16(feats[n] @ W), att[n] = feats[n].w_att
//     256 thr = 4 waves; wave w computes nodes [w*16, w*16+16) x 128 cols.
//     feats staged as bf16 in XOR-swizzled LDS (byte ^= (row&7)<<4).
// ---------------------------------------------------------------------------
__global__ void __launch_bounds__(256)
proj_mfma_kernel(const float* __restrict__ feats,          // [n,128] f32
                 const unsigned short* __restrict__ wfrag, // this matrix's frag set
                 const float* __restrict__ w_att, int wrow, int n_nodes,
                 unsigned short* __restrict__ proj,        // [n,128] bf16
                 float* __restrict__ att)                  // [n] f32
{
    __shared__ unsigned short s_tile[NPB * D];   // 16 KB, swizzled
    __shared__ float s_red[NPB][4];

    const int tid = threadIdx.x;
    const int node0 = blockIdx.x * NPB;

    // stage + convert f32 -> bf16 (coalesced float4 reads, 8B LDS writes)
#pragma unroll
    for (int it = 0; it < 8; ++it) {
        int idx = it * 256 + tid;          // 2048 float4 groups
        int row = idx >> 5, c4 = idx & 31;
        int n = node0 + row;
        float4 v = (n < n_nodes)
                 ? *reinterpret_cast<const float4*>(&feats[(size_t)n * D + c4 * 4])
                 : make_float4(0.f, 0.f, 0.f, 0.f);
        unsigned short h[4];
        h[0] = f32_to_bf16(v.x); h[1] = f32_to_bf16(v.y);
        h[2] = f32_to_bf16(v.z); h[3] = f32_to_bf16(v.w);
        int byte = row * 256 + c4 * 8;
        byte ^= (row & 7) << 4;
        *reinterpret_cast<ushort4*>((char*)s_tile + byte) = *reinterpret_cast<ushort4*>(h);
    }
    __syncthreads();

    const int wv = tid >> 6, lane = tid & 63;

    f32x4 acc[8];
#pragma unroll
    for (int i = 0; i < 8; ++i) acc[i] = {0.f, 0.f, 0.f, 0.f};

    const int arow = wv * 16 + (lane & 15);
#pragma unroll
    for (int ks = 0; ks < 4; ++ks) {
        int abyte = arow * 256 + ks * 64 + (lane >> 4) * 16;
        abyte ^= (arow & 7) << 4;
        short8 a = *reinterpret_cast<const short8*>((char*)s_tile + abyte);
#pragma unroll
        for (int nt = 0; nt < 8; ++nt) {
            short8 b = *reinterpret_cast<const short8*>(wfrag + ((size_t)(ks * 8 + nt) * 64 + lane) * 8);
            acc[nt] = __builtin_amdgcn_mfma_f32_16x16x32_bf16(a, b, acc[nt], 0, 0, 0);
        }
    }

    // C/D: col = lane&15, row = (lane>>4)*4 + r   [verified layout]
#pragma unroll
    for (int nt = 0; nt < 8; ++nt) {
#pragma unroll
        for (int r = 0; r < 4; ++r) {
            int node = node0 + wv * 16 + (lane >> 4) * 4 + r;
            if (node < n_nodes)
                proj[(size_t)node * D + nt * 16 + (lane & 15)] = f32_to_bf16(acc[nt][r]);
        }
    }

    // att scalar: 256 threads = 64 nodes x 4 k-quarters (reads swizzled LDS)
    const int na = tid & 63, kq = tid >> 6;
    float p = 0.f;
#pragma unroll
    for (int k = kq * 32; k < kq * 32 + 32; ++k) {
        int byte = (na * 256 + k * 2) ^ ((na & 7) << 4);
        unsigned short h = *reinterpret_cast<const unsigned short*>((char*)s_tile + byte);
        p += __uint_as_float(((unsigned int)h) << 16) * w_att[wrow + k];
    }
    s_red[na][kq] = p;
    __syncthreads();
    if (tid < NPB) {
        int n = node0 + tid;
        if (n < n_nodes)
            att[n] = s_red[tid][0] + s_red[tid][1] + s_red[tid][2] + s_red[tid][3];
    }
}

// ---------------------------------------------------------------------------
// K2: histogram of edge destinations (counts only)
// ---------------------------------------------------------------------------
__global__ void hist_kernel(const int* __restrict__ edst, int* __restrict__ counts,
                            int n_edge)
{
    int e = blockIdx.x * blockDim.x + threadIdx.x;
    if (e < n_edge) atomicAdd(&counts[edst[e]], 1);
}

// ---------------------------------------------------------------------------
// K3a/b/c: parallel exclusive scan of PADDED counts ((c+3)&~3)
// ---------------------------------------------------------------------------
__global__ void __launch_bounds__(SCAN_T)
scan_block_kernel(const int* __restrict__ counts, int* __restrict__ offsets,
                  int* __restrict__ blocksum, int n)
{
    __shared__ int s_w[4];
    const int blk = blockIdx.x, tid = threadIdx.x;
    const int lane = tid & 63, wid = tid >> 6;
    const int base = blk * SCAN_TILE + tid * SCAN_IT;

    int v[SCAN_IT];
    int tsum = 0;
#pragma unroll
    for (int i = 0; i < SCAN_IT; ++i) {
        v[i] = (base + i < n) ? ((counts[base + i] + 3) & ~3) : 0;
        tsum += v[i];
    }
    int x = tsum;
#pragma unroll
    for (int off = 1; off < 64; off <<= 1) {
        int y = __shfl_up(x, off);
        if (lane >= off) x += y;
    }
    if (lane == 63) s_w[wid] = x;
    __syncthreads();
    if (tid == 0) {
        int a = 0;
#pragma unroll
        for (int w = 0; w < 4; ++w) { int t = s_w[w]; s_w[w] = a; a += t; }
        blocksum[blk] = a;
    }
    __syncthreads();
    int run = s_w[wid] + (x - tsum);
#pragma unroll
    for (int i = 0; i < SCAN_IT; ++i) {
        if (base + i < n) offsets[base + i] = run;
        run += v[i];
    }
}

__global__ void __launch_bounds__(64)
scan_sums_kernel(int* __restrict__ blocksum, int* __restrict__ offsets,
                 int nblk, int n)
{
    const int tid = threadIdx.x;
    int v = (tid < nblk) ? blocksum[tid] : 0;
    int x = v;
#pragma unroll
    for (int off = 1; off < 64; off <<= 1) {
        int y = __shfl_up(x, off);
        if (tid >= off) x += y;
    }
    if (tid < nblk) blocksum[tid] = x - v;   // exclusive
    if (tid == 63) offsets[n] = x;           // grand total (padded)
}

__global__ void scan_fixup_kernel(int* __restrict__ offsets, const int* __restrict__ blocksum,
                                  int* __restrict__ cursor, int n)
{
    int i = blockIdx.x * blockDim.x + threadIdx.x;
    if (i < n) {
        int o = offsets[i] + blocksum[i / SCAN_TILE];
        offsets[i] = o;
        cursor[i] = o;
    }
}

// ---------------------------------------------------------------------------
// K4: fused score + exp + per-dst sums (atomics) + CSR scatter of {src, ew}
// ---------------------------------------------------------------------------
__global__ void hew_scatter_kernel(const int* __restrict__ esrc, const int* __restrict__ edst,
                                   const float* __restrict__ dist,
                                   const float* __restrict__ src_att,
                                   const float* __restrict__ dst_att,
                                   const float* __restrict__ w_att,
                                   int* __restrict__ cursor,
                                   float* __restrict__ sw, float* __restrict__ sd0,
                                   float* __restrict__ sd1,
                                   float2* __restrict__ meta, int n_edge)
{
    int e = blockIdx.x * blockDim.x + threadIdx.x;
    if (e >= n_edge) return;
    int s = esrc[e];
    int d = edst[e];
    float2 dd = *reinterpret_cast<const float2*>(&dist[2 * (size_t)e]);
    float sc = src_att[s] + dst_att[d] + dd.x * w_att[128] + dd.y * w_att[129];
    sc = (sc >= 0.f) ? sc : 0.2f * sc;
    float ew = __expf(sc);
    atomicAdd(&sw[d], ew);
    atomicAdd(&sd0[d], ew * dd.x);
    atomicAdd(&sd1[d], ew * dd.y);
    int pos = atomicAdd(&cursor[d], 1);
    meta[pos] = make_float2(__int_as_float(s), ew);
}

// ---------------------------------------------------------------------------
// K5: wave-per-dst aggregation, branch-free 4-wide gather pipeline.
//     Segments padded to x4 with {s=0, ew=0} entries (zeroed meta).
// ---------------------------------------------------------------------------
__global__ void __launch_bounds__(256)
aggregate_kernel(const int* __restrict__ offsets, const float2* __restrict__ meta,
                 const unsigned short* __restrict__ srcp,   // bf16 [n_src,128]
                 const unsigned short* __restrict__ dstp,   // bf16 [n_dst,128]
                 const float* __restrict__ swp, const float* __restrict__ sd0p,
                 const float* __restrict__ sd1p,
                 const float* __restrict__ w_embed,
                 float* __restrict__ out, int n_dst)
{
    const int wv = threadIdx.x >> 6;
    const int lane = threadIdx.x & 63;
    const int d = blockIdx.x * 4 + wv;
    if (d >= n_dst) return;

    const int c0 = 2 * lane;
    float2* op = reinterpret_cast<float2*>(&out[(size_t)d * D + c0]);

    int begin = __builtin_amdgcn_readfirstlane(offsets[d]);
    int end   = __builtin_amdgcn_readfirstlane(offsets[d + 1]);
    if (begin == end) { *op = make_float2(0.f, 0.f); return; }

    float acc0 = 0.f, acc1 = 0.f;
    for (int i = begin; i < end; i += 4) {
        float2 m0 = meta[i + 0];
        float2 m1 = meta[i + 1];
        float2 m2 = meta[i + 2];
        float2 m3 = meta[i + 3];
        unsigned int r0 = *reinterpret_cast<const unsigned int*>(&srcp[(size_t)__float_as_int(m0.x) * D + c0]);
        unsigned int r1 = *reinterpret_cast<const unsigned int*>(&srcp[(size_t)__float_as_int(m1.x) * D + c0]);
        unsigned int r2 = *reinterpret_cast<const unsigned int*>(&srcp[(size_t)__float_as_int(m2.x) * D + c0]);
        unsigned int r3 = *reinterpret_cast<const unsigned int*>(&srcp[(size_t)__float_as_int(m3.x) * D + c0]);
        acc0 += m0.y * bf16lo(r0); acc1 += m0.y * bf16hi(r0);
        acc0 += m1.y * bf16lo(r1); acc1 += m1.y * bf16hi(r1);
        acc0 += m2.y * bf16lo(r2); acc1 += m2.y * bf16hi(r2);
        acc0 += m3.y * bf16lo(r3); acc1 += m3.y * bf16hi(r3);
    }

    const float inv = 1.f / swp[d];
    const float s0 = sd0p[d], s1 = sd1p[d];
    const float2 wd0 = *reinterpret_cast<const float2*>(&w_embed[128 * D + c0]);
    const float2 wd1 = *reinterpret_cast<const float2*>(&w_embed[129 * D + c0]);
    unsigned int rd = *reinterpret_cast<const unsigned int*>(&dstp[(size_t)d * D + c0]);

    float o0 = (acc0 + s0 * wd0.x + s1 * wd1.x) * inv + bf16lo(rd);
    float o1 = (acc1 + s0 * wd0.y + s1 * wd1.y) * inv + bf16hi(rd);
    *op = make_float2(fmaxf(o0, 0.f), fmaxf(o1, 0.f));
}

// ---------------------------------------------------------------------------
extern "C" void kernel_launch(void* const* d_in, const int* in_sizes, int n_in,
                              void* d_out, int out_size, void* d_ws, size_t ws_size,
                              hipStream_t stream)
{
    const float* src_feat = (const float*)d_in[0];   // [N_SRC,128]
    const int*   esrc     = (const int*)d_in[1];     // [E]
    const float* dst_feat = (const float*)d_in[2];   // [N_DST,128]
    const int*   edst     = (const int*)d_in[3];     // [E]
    const float* dist     = (const float*)d_in[4];   // [E,2]
    const float* w_att    = (const float*)d_in[5];   // [258]
    const float* w_embed  = (const float*)d_in[6];   // [258,128]

    const int n_src  = in_sizes[0] / D;
    const int n_edge = in_sizes[1];
    const int n_dst  = in_sizes[2] / D;

    // ---- workspace carve-up (256B-aligned) ----
    char* p = (char*)d_ws;
    auto carve = [&p](size_t bytes) {
        char* r = p;
        p += (bytes + 255) & ~size_t(255);
        return r;
    };
    unsigned short* src_projb = (unsigned short*)carve((size_t)n_src * D * 2);  // bf16
    unsigned short* dst_projb = (unsigned short*)carve((size_t)n_dst * D * 2);  // bf16
    float* src_att   = (float*)carve((size_t)n_src * 4);
    float* dst_att   = (float*)carve((size_t)n_dst * 4);
    int*   counts    = (int*)carve((size_t)4 * n_dst * 4);   // counts, sw, sd0, sd1
    float* sw        = (float*)(counts + n_dst);
    float* sd0       = (float*)(counts + 2 * n_dst);
    float* sd1       = (float*)(counts + 3 * n_dst);
    int*   offsets   = (int*)carve((size_t)(n_dst + 1) * 4);
    int*   cursor    = (int*)carve((size_t)n_dst * 4);
    int*   blocksum  = (int*)carve(64 * 4);
    unsigned short* w_frag = (unsigned short*)carve(2 * 4 * 8 * 64 * 8 * 2);  // 64 KB
    float2* meta     = (float2*)carve(((size_t)n_edge + 4 * (size_t)n_dst) * 8);
    (void)ws_size;

    // K0: W -> bf16 fragment layout
    wconv_kernel<<<16, 256, 0, stream>>>(w_embed, w_frag);

    // K1: MFMA node projections (both bf16 out)
    proj_mfma_kernel<<<(n_src + NPB - 1) / NPB, 256, 0, stream>>>(
        src_feat, w_frag, w_att, 0, n_src, src_projb, src_att);
    proj_mfma_kernel<<<(n_dst + NPB - 1) / NPB, 256, 0, stream>>>(
        dst_feat, w_frag + 16384, w_att, 130, n_dst, dst_projb, dst_att);

    // zero counts+sums and (padded) meta
    hipMemsetAsync(counts, 0, (size_t)4 * n_dst * 4, stream);
    hipMemsetAsync(meta, 0, ((size_t)n_edge + 4 * (size_t)n_dst) * 8, stream);

    // K2: histogram
    hist_kernel<<<(n_edge + 255) / 256, 256, 0, stream>>>(edst, counts, n_edge);

    // K3: padded exclusive scan -> offsets, cursor
    const int nblk = (n_dst + SCAN_TILE - 1) / SCAN_TILE;
    scan_block_kernel<<<nblk, SCAN_T, 0, stream>>>(counts, offsets, blocksum, n_dst);
    scan_sums_kernel<<<1, 64, 0, stream>>>(blocksum, offsets, nblk, n_dst);
    scan_fixup_kernel<<<(n_dst + 255) / 256, 256, 0, stream>>>(offsets, blocksum, cursor, n_dst);

    // K4: fused score/exp/sums/scatter
    hew_scatter_kernel<<<(n_edge + 255) / 256, 256, 0, stream>>>(
        esrc, edst, dist, src_att, dst_att, w_att, cursor, sw, sd0, sd1, meta, n_edge);

    // K5: aggregation
    aggregate_kernel<<<(n_dst + 3) / 4, 256, 0, stream>>>(
        offsets, meta, src_projb, dst_projb, sw, sd0, sd1, w_embed,
        (float*)d_out, n_dst);
}

// Round 4
// 163.665 us; speedup vs baseline: 1.6663x; 1.6663x over previous
//
#include <hip/hip_runtime.h>
#include <hip/hip_bf16.h>

#define D 128
#define NPB 64
#define SCAN_T 256
#define SCAN_IT 8
#define SCAN_TILE (SCAN_T * SCAN_IT)   // 2048

typedef __attribute__((ext_vector_type(8))) short short8;   // 8 bf16 (4 VGPRs)
typedef __attribute__((ext_vector_type(4))) float f32x4;

static __device__ __forceinline__ unsigned short f32_to_bf16(float f) {
    unsigned int u = __float_as_uint(f);
    u = (u + 0x7FFFu + ((u >> 16) & 1u)) >> 16;   // RNE
    return (unsigned short)u;
}
static __device__ __forceinline__ float bf16lo(unsigned int r) {
    return __uint_as_float(r << 16);
}
static __device__ __forceinline__ float bf16hi(unsigned int r) {
    return __uint_as_float(r & 0xFFFF0000u);
}

// ---------------------------------------------------------------------------
// K0: convert w_embed rows into MFMA B-fragment layout (bf16), two sets:
//     set0 = rows 0..127 (src proj), set1 = rows 130..257 (dst proj).
// ---------------------------------------------------------------------------
__global__ void __launch_bounds__(256)
wconv_kernel(const float* __restrict__ w_embed, unsigned short* __restrict__ w_frag)
{
    int t = blockIdx.x * 256 + threadIdx.x;     // 4096 lane-frags total
    if (t >= 4096) return;
    int set  = t >> 11;
    int ks   = (t >> 9) & 3;
    int nt   = (t >> 6) & 7;
    int lane = t & 63;
    int wrow0 = set ? 130 : 0;
    int col   = nt * 16 + (lane & 15);
    int kbase = ks * 32 + (lane >> 4) * 8;
    unsigned short* dst = w_frag + (size_t)t * 8;
#pragma unroll
    for (int j = 0; j < 8; ++j)
        dst[j] = f32_to_bf16(w_embed[(size_t)(wrow0 + kbase + j) * D + col]);
}

// ---------------------------------------------------------------------------
// K1: MFMA node projection.  proj[n] = bf16(feats[n] @ W), att[n] = feats[n].w_att
//     256 thr = 4 waves; wave w computes nodes [w*16, w*16+16) x 128 cols.
//     feats staged as bf16 in XOR-swizzled LDS (byte ^= (row&7)<<4).
// ---------------------------------------------------------------------------
__global__ void __launch_bounds__(256)
proj_mfma_kernel(const float* __restrict__ feats,          // [n,128] f32
                 const unsigned short* __restrict__ wfrag, // this matrix's frag set
                 const float* __restrict__ w_att, int wrow, int n_nodes,
                 unsigned short* __restrict__ proj,        // [n,128] bf16
                 float* __restrict__ att)                  // [n] f32
{
    __shared__ unsigned short s_tile[NPB * D];   // 16 KB, swizzled
    __shared__ float s_red[NPB][4];

    const int tid = threadIdx.x;
    const int node0 = blockIdx.x * NPB;

    // stage + convert f32 -> bf16 (coalesced float4 reads, 8B LDS writes)
#pragma unroll
    for (int it = 0; it < 8; ++it) {
        int idx = it * 256 + tid;          // 2048 float4 groups
        int row = idx >> 5, c4 = idx & 31;
        int n = node0 + row;
        float4 v = (n < n_nodes)
                 ? *reinterpret_cast<const float4*>(&feats[(size_t)n * D + c4 * 4])
                 : make_float4(0.f, 0.f, 0.f, 0.f);
        unsigned short h[4];
        h[0] = f32_to_bf16(v.x); h[1] = f32_to_bf16(v.y);
        h[2] = f32_to_bf16(v.z); h[3] = f32_to_bf16(v.w);
        int byte = row * 256 + c4 * 8;
        byte ^= (row & 7) << 4;
        *reinterpret_cast<ushort4*>((char*)s_tile + byte) = *reinterpret_cast<ushort4*>(h);
    }
    __syncthreads();

    const int wv = tid >> 6, lane = tid & 63;

    f32x4 acc[8];
#pragma unroll
    for (int i = 0; i < 8; ++i) acc[i] = {0.f, 0.f, 0.f, 0.f};

    const int arow = wv * 16 + (lane & 15);
#pragma unroll
    for (int ks = 0; ks < 4; ++ks) {
        int abyte = arow * 256 + ks * 64 + (lane >> 4) * 16;
        abyte ^= (arow & 7) << 4;
        short8 a = *reinterpret_cast<const short8*>((char*)s_tile + abyte);
#pragma unroll
        for (int nt = 0; nt < 8; ++nt) {
            short8 b = *reinterpret_cast<const short8*>(wfrag + ((size_t)(ks * 8 + nt) * 64 + lane) * 8);
            acc[nt] = __builtin_amdgcn_mfma_f32_16x16x32_bf16(a, b, acc[nt], 0, 0, 0);
        }
    }

    // C/D: col = lane&15, row = (lane>>4)*4 + r
#pragma unroll
    for (int nt = 0; nt < 8; ++nt) {
#pragma unroll
        for (int r = 0; r < 4; ++r) {
            int node = node0 + wv * 16 + (lane >> 4) * 4 + r;
            if (node < n_nodes)
                proj[(size_t)node * D + nt * 16 + (lane & 15)] = f32_to_bf16(acc[nt][r]);
        }
    }

    // att scalar: 256 threads = 64 nodes x 4 k-quarters (reads swizzled LDS)
    const int na = tid & 63, kq = tid >> 6;
    float p = 0.f;
#pragma unroll
    for (int k = kq * 32; k < kq * 32 + 32; ++k) {
        int byte = (na * 256 + k * 2) ^ ((na & 7) << 4);
        unsigned short h = *reinterpret_cast<const unsigned short*>((char*)s_tile + byte);
        p += __uint_as_float(((unsigned int)h) << 16) * w_att[wrow + k];
    }
    s_red[na][kq] = p;
    __syncthreads();
    if (tid < NPB) {
        int n = node0 + tid;
        if (n < n_nodes)
            att[n] = s_red[tid][0] + s_red[tid][1] + s_red[tid][2] + s_red[tid][3];
    }
}

// ---------------------------------------------------------------------------
// K2: histogram of edge destinations (counts only)
// ---------------------------------------------------------------------------
__global__ void hist_kernel(const int* __restrict__ edst, int* __restrict__ counts,
                            int n_edge)
{
    int e = blockIdx.x * blockDim.x + threadIdx.x;
    if (e < n_edge) atomicAdd(&counts[edst[e]], 1);
}

// ---------------------------------------------------------------------------
// K3a/b/c: parallel exclusive scan of PADDED counts ((c+3)&~3)
// ---------------------------------------------------------------------------
__global__ void __launch_bounds__(SCAN_T)
scan_block_kernel(const int* __restrict__ counts, int* __restrict__ offsets,
                  int* __restrict__ blocksum, int n)
{
    __shared__ int s_w[4];
    const int blk = blockIdx.x, tid = threadIdx.x;
    const int lane = tid & 63, wid = tid >> 6;
    const int base = blk * SCAN_TILE + tid * SCAN_IT;

    int v[SCAN_IT];
    int tsum = 0;
#pragma unroll
    for (int i = 0; i < SCAN_IT; ++i) {
        v[i] = (base + i < n) ? ((counts[base + i] + 3) & ~3) : 0;
        tsum += v[i];
    }
    int x = tsum;
#pragma unroll
    for (int off = 1; off < 64; off <<= 1) {
        int y = __shfl_up(x, off);
        if (lane >= off) x += y;
    }
    if (lane == 63) s_w[wid] = x;
    __syncthreads();
    if (tid == 0) {
        int a = 0;
#pragma unroll
        for (int w = 0; w < 4; ++w) { int t = s_w[w]; s_w[w] = a; a += t; }
        blocksum[blk] = a;
    }
    __syncthreads();
    int run = s_w[wid] + (x - tsum);
#pragma unroll
    for (int i = 0; i < SCAN_IT; ++i) {
        if (base + i < n) offsets[base + i] = run;
        run += v[i];
    }
}

__global__ void __launch_bounds__(64)
scan_sums_kernel(int* __restrict__ blocksum, int* __restrict__ offsets,
                 int nblk, int n)
{
    const int tid = threadIdx.x;
    int v = (tid < nblk) ? blocksum[tid] : 0;
    int x = v;
#pragma unroll
    for (int off = 1; off < 64; off <<= 1) {
        int y = __shfl_up(x, off);
        if (tid >= off) x += y;
    }
    if (tid < nblk) blocksum[tid] = x - v;   // exclusive
    if (tid == 63) offsets[n] = x;           // grand total (padded)
}

__global__ void scan_fixup_kernel(int* __restrict__ offsets, const int* __restrict__ blocksum,
                                  int* __restrict__ cursor, int n)
{
    int i = blockIdx.x * blockDim.x + threadIdx.x;
    if (i < n) {
        int o = offsets[i] + blocksum[i / SCAN_TILE];
        offsets[i] = o;
        cursor[i] = o;
    }
}

// ---------------------------------------------------------------------------
// K4: per-edge score + exp, scatter packed meta {src, ew, d0, d1} into CSR.
//     Single int atomic per edge (cursor), no float atomics.
// ---------------------------------------------------------------------------
__global__ void scatter_meta_kernel(const int* __restrict__ esrc, const int* __restrict__ edst,
                                    const float* __restrict__ dist,
                                    const float* __restrict__ src_att,
                                    const float* __restrict__ dst_att,
                                    const float* __restrict__ w_att,
                                    int* __restrict__ cursor,
                                    float4* __restrict__ meta, int n_edge)
{
    int e = blockIdx.x * blockDim.x + threadIdx.x;
    if (e >= n_edge) return;
    int s = esrc[e];
    int d = edst[e];
    float2 dd = *reinterpret_cast<const float2*>(&dist[2 * (size_t)e]);
    float sc = src_att[s] + dst_att[d] + dd.x * w_att[128] + dd.y * w_att[129];
    sc = (sc >= 0.f) ? sc : 0.2f * sc;
    float ew = __expf(sc);
    int pos = atomicAdd(&cursor[d], 1);
    meta[pos] = make_float4(__int_as_float(s), ew, dd.x, dd.y);
}

// ---------------------------------------------------------------------------
// K5: wave-per-dst aggregation, branch-free 4-wide gather pipeline.
//     Segments padded to x4 with ew=0 entries (zeroed meta).
//     Offsets scalarized (readfirstlane) -> meta reads become s_load (uniform);
//     every lane redundantly accumulates sw/swd0/swd1 in-register (VALU idle).
// ---------------------------------------------------------------------------
__global__ void __launch_bounds__(256)
aggregate_kernel(const int* __restrict__ offsets, const float4* __restrict__ meta,
                 const unsigned short* __restrict__ srcp,   // bf16 [n_src,128]
                 const unsigned short* __restrict__ dstp,   // bf16 [n_dst,128]
                 const float* __restrict__ w_embed,
                 float* __restrict__ out, int n_dst)
{
    const int wv = threadIdx.x >> 6;
    const int lane = threadIdx.x & 63;
    const int d = blockIdx.x * 4 + wv;
    if (d >= n_dst) return;

    const int c0 = 2 * lane;
    float2* op = reinterpret_cast<float2*>(&out[(size_t)d * D + c0]);

    int begin = __builtin_amdgcn_readfirstlane(offsets[d]);
    int end   = __builtin_amdgcn_readfirstlane(offsets[d + 1]);
    if (begin == end) { *op = make_float2(0.f, 0.f); return; }

    float acc0 = 0.f, acc1 = 0.f;
    float sw = 0.f, swd0 = 0.f, swd1 = 0.f;

    for (int i = begin; i < end; i += 4) {
        float4 m0 = meta[i + 0];
        float4 m1 = meta[i + 1];
        float4 m2 = meta[i + 2];
        float4 m3 = meta[i + 3];
        unsigned int r0 = *reinterpret_cast<const unsigned int*>(&srcp[(size_t)__float_as_int(m0.x) * D + c0]);
        unsigned int r1 = *reinterpret_cast<const unsigned int*>(&srcp[(size_t)__float_as_int(m1.x) * D + c0]);
        unsigned int r2 = *reinterpret_cast<const unsigned int*>(&srcp[(size_t)__float_as_int(m2.x) * D + c0]);
        unsigned int r3 = *reinterpret_cast<const unsigned int*>(&srcp[(size_t)__float_as_int(m3.x) * D + c0]);
        acc0 += m0.y * bf16lo(r0); acc1 += m0.y * bf16hi(r0);
        acc0 += m1.y * bf16lo(r1); acc1 += m1.y * bf16hi(r1);
        acc0 += m2.y * bf16lo(r2); acc1 += m2.y * bf16hi(r2);
        acc0 += m3.y * bf16lo(r3); acc1 += m3.y * bf16hi(r3);
        sw   += m0.y + m1.y + m2.y + m3.y;
        swd0 += m0.y * m0.z + m1.y * m1.z + m2.y * m2.z + m3.y * m3.z;
        swd1 += m0.y * m0.w + m1.y * m1.w + m2.y * m2.w + m3.y * m3.w;
    }

    const float inv = 1.f / sw;
    const float2 wd0 = *reinterpret_cast<const float2*>(&w_embed[128 * D + c0]);
    const float2 wd1 = *reinterpret_cast<const float2*>(&w_embed[129 * D + c0]);
    unsigned int rd = *reinterpret_cast<const unsigned int*>(&dstp[(size_t)d * D + c0]);

    float o0 = (acc0 + swd0 * wd0.x + swd1 * wd1.x) * inv + bf16lo(rd);
    float o1 = (acc0 * 0.f + acc1 + swd0 * wd0.y + swd1 * wd1.y) * inv + bf16hi(rd);
    *op = make_float2(fmaxf(o0, 0.f), fmaxf(o1, 0.f));
}

// ---------------------------------------------------------------------------
extern "C" void kernel_launch(void* const* d_in, const int* in_sizes, int n_in,
                              void* d_out, int out_size, void* d_ws, size_t ws_size,
                              hipStream_t stream)
{
    const float* src_feat = (const float*)d_in[0];   // [N_SRC,128]
    const int*   esrc     = (const int*)d_in[1];     // [E]
    const float* dst_feat = (const float*)d_in[2];   // [N_DST,128]
    const int*   edst     = (const int*)d_in[3];     // [E]
    const float* dist     = (const float*)d_in[4];   // [E,2]
    const float* w_att    = (const float*)d_in[5];   // [258]
    const float* w_embed  = (const float*)d_in[6];   // [258,128]

    const int n_src  = in_sizes[0] / D;
    const int n_edge = in_sizes[1];
    const int n_dst  = in_sizes[2] / D;

    // ---- workspace carve-up (256B-aligned) ----
    char* p = (char*)d_ws;
    auto carve = [&p](size_t bytes) {
        char* r = p;
        p += (bytes + 255) & ~size_t(255);
        return r;
    };
    unsigned short* src_projb = (unsigned short*)carve((size_t)n_src * D * 2);  // bf16
    unsigned short* dst_projb = (unsigned short*)carve((size_t)n_dst * D * 2);  // bf16
    float* src_att   = (float*)carve((size_t)n_src * 4);
    float* dst_att   = (float*)carve((size_t)n_dst * 4);
    int*   counts    = (int*)carve((size_t)n_dst * 4);
    int*   offsets   = (int*)carve((size_t)(n_dst + 1) * 4);
    int*   cursor    = (int*)carve((size_t)n_dst * 4);
    int*   blocksum  = (int*)carve(64 * 4);
    unsigned short* w_frag = (unsigned short*)carve(2 * 4 * 8 * 64 * 8 * 2);  // 64 KB
    float4* meta     = (float4*)carve(((size_t)n_edge + 4 * (size_t)n_dst) * 16);
    (void)ws_size;

    // K0: W -> bf16 fragment layout
    wconv_kernel<<<16, 256, 0, stream>>>(w_embed, w_frag);

    // K1: MFMA node projections (both bf16 out)
    proj_mfma_kernel<<<(n_src + NPB - 1) / NPB, 256, 0, stream>>>(
        src_feat, w_frag, w_att, 0, n_src, src_projb, src_att);
    proj_mfma_kernel<<<(n_dst + NPB - 1) / NPB, 256, 0, stream>>>(
        dst_feat, w_frag + 16384, w_att, 130, n_dst, dst_projb, dst_att);

    // zero counts and (padded) meta
    hipMemsetAsync(counts, 0, (size_t)n_dst * 4, stream);
    hipMemsetAsync(meta, 0, ((size_t)n_edge + 4 * (size_t)n_dst) * 16, stream);

    // K2: histogram
    hist_kernel<<<(n_edge + 255) / 256, 256, 0, stream>>>(edst, counts, n_edge);

    // K3: padded exclusive scan -> offsets, cursor
    const int nblk = (n_dst + SCAN_TILE - 1) / SCAN_TILE;
    scan_block_kernel<<<nblk, SCAN_T, 0, stream>>>(counts, offsets, blocksum, n_dst);
    scan_sums_kernel<<<1, 64, 0, stream>>>(blocksum, offsets, nblk, n_dst);
    scan_fixup_kernel<<<(n_dst + 255) / 256, 256, 0, stream>>>(offsets, blocksum, cursor, n_dst);

    // K4: score/exp + CSR scatter (single atomic per edge)
    scatter_meta_kernel<<<(n_edge + 255) / 256, 256, 0, stream>>>(
        esrc, edst, dist, src_att, dst_att, w_att, cursor, meta, n_edge);

    // K5: aggregation (sums computed redundantly in-register)
    aggregate_kernel<<<(n_dst + 3) / 4, 256, 0, stream>>>(
        offsets, meta, src_projb, dst_projb, w_embed, (float*)d_out, n_dst);
}